// Round 6
// baseline (435.864 us; speedup 1.0000x reference)
//
#include <hip/hip_runtime.h>
#include <hip/hip_bf16.h>

typedef __attribute__((ext_vector_type(8))) short short8;
typedef __attribute__((ext_vector_type(16))) float f32x16;
typedef unsigned short u16;

// ---------- helpers ----------
__device__ __forceinline__ u16 f2bf(float f) {
  union { float f; unsigned u; } v; v.f = f;
  unsigned r = v.u + 0x7fffu + ((v.u >> 16) & 1u);
  return (u16)(r >> 16);
}
__device__ __forceinline__ float bf2f(u16 u) {
  union { unsigned u; float f; } v; v.u = ((unsigned)u) << 16;
  return v.f;
}
__device__ __forceinline__ void gload16(const void* g, void* l) {
  __builtin_amdgcn_global_load_lds(
      (const __attribute__((address_space(1))) unsigned*)g,
      (__attribute__((address_space(3))) unsigned*)l, 16, 0, 0);
}

#define FENCE asm volatile("" ::: "memory")
#define SB0 __builtin_amdgcn_sched_barrier(0)
#define BAR do { FENCE; __builtin_amdgcn_s_barrier(); FENCE; } while (0)

// ---------- fused LayerNorm x3: fp32 [rows,1024] -> bf16 ----------
__global__ __launch_bounds__(256)
void ln3(const float* __restrict__ refp, const float* __restrict__ pose,
         const float* __restrict__ img, const float* __restrict__ gamma,
         const float* __restrict__ beta, u16* __restrict__ oA,
         u16* __restrict__ oB, u16* __restrict__ oC) {
  const int row = blockIdx.x;
  const int tid = threadIdx.x;
  const float* X = (blockIdx.y == 0) ? refp : (blockIdx.y == 1) ? pose : img;
  u16* Y = (blockIdx.y == 0) ? oA : (blockIdx.y == 1) ? oB : oC;
  const long base = (long)row * 1024 + tid * 4;
  float4 x = *(const float4*)(X + base);
  float s = x.x + x.y + x.z + x.w;
  float q = x.x * x.x + x.y * x.y + x.z * x.z + x.w * x.w;
#pragma unroll
  for (int o = 32; o > 0; o >>= 1) {
    s += __shfl_xor(s, o);
    q += __shfl_xor(q, o);
  }
  __shared__ float rs[4], rq[4];
  if ((tid & 63) == 0) { rs[tid >> 6] = s; rq[tid >> 6] = q; }
  __syncthreads();
  s = rs[0] + rs[1] + rs[2] + rs[3];
  q = rq[0] + rq[1] + rq[2] + rq[3];
  float mu = s * (1.f / 1024.f);
  float var = q * (1.f / 1024.f) - mu * mu;
  float rstd = rsqrtf(var + 1e-5f);
  float4 g = *(const float4*)(gamma + tid * 4);
  float4 b = *(const float4*)(beta + tid * 4);
  ushort4 o4;
  o4.x = f2bf((x.x - mu) * rstd * g.x + b.x);
  o4.y = f2bf((x.y - mu) * rstd * g.y + b.y);
  o4.z = f2bf((x.z - mu) * rstd * g.z + b.z);
  o4.w = f2bf((x.w - mu) * rstd * g.w + b.w);
  *(ushort4*)(Y + base) = o4;
}

// ---------- fused fp32 -> bf16 convert of all 4 weight matrices ----------
__global__ __launch_bounds__(256)
void cvt_all(const float* __restrict__ Wq, const float* __restrict__ Wk,
             const float* __restrict__ Wv, const float* __restrict__ Wo,
             u16* __restrict__ oq, u16* __restrict__ ok, u16* __restrict__ ov,
             u16* __restrict__ oo) {
  int i = blockIdx.x * 256 + threadIdx.x;  // float4 index; total 983040
  const int W1 = 262144;                   // 1024*1024/4
  const float* src;
  u16* dst;
  int j;
  if (i < W1) { src = Wq; dst = oq; j = i; }
  else if (i < 2 * W1) { src = Wk; dst = ok; j = i - W1; }
  else if (i < 3 * W1) { src = Wv; dst = ov; j = i - 2 * W1; }
  else { src = Wo; dst = oo; j = i - 3 * W1; }
  float4 x = ((const float4*)src)[j];
  ushort4 o;
  o.x = f2bf(x.x); o.y = f2bf(x.y); o.z = f2bf(x.z); o.w = f2bf(x.w);
  ((ushort4*)dst)[j] = o;
}

// ---------- 256x256 GEMM, 32x32x16 MFMA, 2-tile-unrolled quadrant schedule ----------
// C' = A·B^T, A [M,K], B [N,K], K-contiguous. Output transposed: out[c, r].
// Per wave (2Mx4N of 8): C 128x64 = 4 mi-blocks x 2 ni-blocks of 32x32.
// 32x32x16 layouts: A/B row|col = lane&31, k = 8*(lane>>5)+j;
//                   C: col=lane&31, row=8*(reg>>2)+4*(lane>>5)+(reg&3).
// MODE 0: bf16 out[c*M + r] = acc + bias[r]
// MODE 1: bf16 out[cb + c*M + r] = exp(acc*scale); atomicAdd rsum[tz*2048+c]
// MODE 2: (direct orientation) bf16 out[b2*2^21 + c*2048 + (r&2047)] = acc + bias[c]
// MODE 3: bf16 out[cb + c*M + r] = acc / rsum[tz*2048+c] + R1 + R2
// MODE 4: fp32 out[c*M + r] = acc + bias[r]
template <int MODE>
__global__ __launch_bounds__(512, 2)
void gemm256(const u16* __restrict__ A, const u16* __restrict__ B,
             const float* __restrict__ bias, void* __restrict__ Cp,
             const u16* __restrict__ R1, const u16* __restrict__ R2,
             float* __restrict__ rsum,
             int M, int N, int K, long sA, long sB, long sC, float scale,
             int ntx, int nty, int g, int fdim) {
  extern __shared__ char lds[];
  // ---- logical tile mapping (XCD-chunked) ----
  const int nwg = gridDim.x;
  const int chunk = nwg >> 3;
  int l = (blockIdx.x & 7) * chunk + (blockIdx.x >> 3);
  const int per = ntx * nty;
  const int tz = l / per;
  int li = l - tz * per;
  const int ns = fdim ? nty : ntx;
  const int fi = li % g;
  const int s_ = (li / g) % ns;
  const int fB2 = li / (g * ns);
  const int f = fB2 * g + fi;
  const int tx = fdim ? f : s_;
  const int ty = fdim ? s_ : f;

  const u16* Ab = A + (long)tz * sA;
  const u16* Bb = B + (long)tz * sB;
  const long cb = (long)tz * sC;

  const int tid = threadIdx.x;
  const int lane = tid & 63;
  const int wid = tid >> 6;
  const int wr = wid >> 2;   // 0..1
  const int wc = wid & 3;    // 0..3
  const long rowBase = (long)ty * 256;
  const long colBase = (long)tx * 256;
  const int l31 = lane & 31;
  const int hi = lane >> 5;  // 0..1
  const int nt = K >> 6;

  // loop-invariant LDS read offsets (swizzled); row&7 == l31&7 (mi/wr strides %8==0)
  int chA[4];
#pragma unroll
  for (int ks = 0; ks < 4; ++ks) chA[ks] = ((2 * ks + hi) ^ (l31 & 7)) * 16;
  const int aB2 = (wr * 128 + l31) * 128;          // + mi*4096 (+buf*65536)
  const int bB2 = 32768 + (wc * 64 + l31) * 128;   // + ni*4096 (+buf*65536)

#define LDA32(BUF, mi, ks) \
  (*(const short8*)(lds + (BUF) * 65536 + aB2 + (mi) * 4096 + chA[ks]))
#define LDB32(BUF, ni, ks) \
  (*(const short8*)(lds + (BUF) * 65536 + bB2 + (ni) * 4096 + chA[ks]))

  // stage half-tile h (128 rows x 64 cols) of A (bOff=0) or B (bOff=32768) into buf
  auto stage = [&](const u16* __restrict__ gb, long rcBase, int t, int h, int bOff, int buf) {
    char* base = lds + buf * 65536 + bOff + h * 16384;
    const long kk = (long)t << 6;
#pragma unroll
    for (int i = 0; i < 2; ++i) {
      const int o = i * 8192 + tid * 16;   // linear byte in half-tile
      const int row = o >> 7;              // 0..127
      const int cs = (o >> 4) & 7;         // 16B chunk slot
      const long gr = rcBase + h * 128 + row;
      const long gk = kk + (long)((cs ^ (row & 7)) << 3);
      gload16(gb + gr * (long)K + gk, base + o);
    }
  };

  f32x16 acc[4][2] = {};
  short8 ar[2][4];  // current mi-pair x 4 ks
  short8 br[2][4];  // both ni x 4 ks

#define RDA(BUF, M0)                                          \
  _Pragma("unroll") for (int mm = 0; mm < 2; ++mm)            \
  _Pragma("unroll") for (int ks = 0; ks < 4; ++ks)            \
    ar[mm][ks] = LDA32(BUF, (M0) + mm, ks);
#define RDB(BUF, NI)                                          \
  _Pragma("unroll") for (int ks = 0; ks < 4; ++ks)            \
    br[NI][ks] = LDB32(BUF, NI, ks);
#define MFMAQ(M0, NI)                                                            \
  __builtin_amdgcn_s_setprio(1);                                                 \
  _Pragma("unroll") for (int ks = 0; ks < 4; ++ks)                               \
  _Pragma("unroll") for (int mm = 0; mm < 2; ++mm)                               \
      acc[(M0) + mm][NI] = __builtin_amdgcn_mfma_f32_32x32x16_bf16(              \
          ar[mm][ks], br[NI][ks], acc[(M0) + mm][NI], 0, 0, 0);                  \
  __builtin_amdgcn_s_setprio(0);

#define GTILE(T, BUF)                                                      \
  do {                                                                     \
    RDA(BUF, 0);                                                           \
    RDB(BUF, 0);                                                           \
    if ((T) + 1 < nt) stage(Ab, rowBase, (T) + 1, 1, 0, (BUF) ^ 1);        \
    BAR; SB0; MFMAQ(0, 0); SB0; BAR;                                       \
    RDB(BUF, 1);                                                           \
    BAR; SB0; MFMAQ(0, 1); SB0; BAR;                                       \
    RDA(BUF, 2);                                                           \
    if ((T) + 2 < nt) stage(Bb, colBase, (T) + 2, 0, 32768, BUF);          \
    BAR; SB0; MFMAQ(2, 0); SB0; BAR;                                       \
    if ((T) + 2 < nt) {                                                    \
      stage(Bb, colBase, (T) + 2, 1, 32768, BUF);                          \
      stage(Ab, rowBase, (T) + 2, 0, 0, BUF);                              \
      asm volatile("s_waitcnt vmcnt(6)" ::: "memory");                     \
    } else {                                                               \
      asm volatile("s_waitcnt vmcnt(0)" ::: "memory");                     \
    }                                                                      \
    BAR; SB0; MFMAQ(2, 1); SB0; BAR;                                       \
  } while (0)

  // prologue: tile0 full into buf0; tile1 (A h0, B h0, B h1) into buf1
  stage(Ab, rowBase, 0, 0, 0, 0);
  stage(Ab, rowBase, 0, 1, 0, 0);
  stage(Bb, colBase, 0, 0, 32768, 0);
  stage(Bb, colBase, 0, 1, 32768, 0);
  if (nt > 1) {
    stage(Ab, rowBase, 1, 0, 0, 1);
    stage(Bb, colBase, 1, 0, 32768, 1);
    stage(Bb, colBase, 1, 1, 32768, 1);
    asm volatile("s_waitcnt vmcnt(6)" ::: "memory");
  } else {
    asm volatile("s_waitcnt vmcnt(0)" ::: "memory");
  }
  BAR;

  for (int tt = 0; tt < nt; tt += 2) {
    GTILE(tt, 0);
    GTILE(tt + 1, 1);
  }

  // ---------- epilogue ----------
  // per acc[mi][ni]: c = colBase + wc*64 + ni*32 + l31;
  // rows: quad q -> r = rowBase + wr*128 + mi*32 + 8q + 4*hi, regs 4q..4q+3.
  if (MODE == 1) {
#pragma unroll
    for (int ni = 0; ni < 2; ++ni) {
      const long c = colBase + wc * 64 + ni * 32 + l31;
      float ps = 0.f;
#pragma unroll
      for (int mi = 0; mi < 4; ++mi) {
        f32x16 v = acc[mi][ni];
#pragma unroll
        for (int q = 0; q < 4; ++q) {
          const long r = rowBase + wr * 128 + mi * 32 + q * 8 + hi * 4;
          float e0 = __expf(v[4 * q + 0] * scale), e1 = __expf(v[4 * q + 1] * scale);
          float e2 = __expf(v[4 * q + 2] * scale), e3 = __expf(v[4 * q + 3] * scale);
          ps += (e0 + e1) + (e2 + e3);
          ushort4 o;
          o.x = f2bf(e0); o.y = f2bf(e1); o.z = f2bf(e2); o.w = f2bf(e3);
          *(ushort4*)((u16*)Cp + cb + c * (long)M + r) = o;
        }
      }
      ps += __shfl_xor(ps, 32);
      if (lane < 32) atomicAdd(&rsum[(long)tz * 2048 + c], ps);
    }
  } else if (MODE == 3) {
#pragma unroll
    for (int ni = 0; ni < 2; ++ni) {
      const long c = colBase + wc * 64 + ni * 32 + l31;
      const float inv = 1.f / rsum[(long)tz * 2048 + c];
#pragma unroll
      for (int mi = 0; mi < 4; ++mi) {
        f32x16 v = acc[mi][ni];
#pragma unroll
        for (int q = 0; q < 4; ++q) {
          const long r = rowBase + wr * 128 + mi * 32 + q * 8 + hi * 4;
          const long idx = cb + c * (long)M + r;
          ushort4 r1 = *(const ushort4*)(R1 + idx);
          ushort4 r2 = *(const ushort4*)(R2 + idx);
          ushort4 o;
          o.x = f2bf(v[4 * q + 0] * inv + bf2f(r1.x) + bf2f(r2.x));
          o.y = f2bf(v[4 * q + 1] * inv + bf2f(r1.y) + bf2f(r2.y));
          o.z = f2bf(v[4 * q + 2] * inv + bf2f(r1.z) + bf2f(r2.z));
          o.w = f2bf(v[4 * q + 3] * inv + bf2f(r1.w) + bf2f(r2.w));
          *(ushort4*)((u16*)Cp + idx) = o;
        }
      }
    }
  } else {
#pragma unroll
    for (int mi = 0; mi < 4; ++mi) {
#pragma unroll
      for (int ni = 0; ni < 2; ++ni) {
        const long c = colBase + wc * 64 + ni * 32 + l31;
        f32x16 v = acc[mi][ni];
#pragma unroll
        for (int q = 0; q < 4; ++q) {
          const long r = rowBase + wr * 128 + mi * 32 + q * 8 + hi * 4;
          if (MODE == 0) {
            float4 bb = *(const float4*)(bias + r);
            ushort4 o;
            o.x = f2bf(v[4 * q + 0] + bb.x); o.y = f2bf(v[4 * q + 1] + bb.y);
            o.z = f2bf(v[4 * q + 2] + bb.z); o.w = f2bf(v[4 * q + 3] + bb.w);
            *(ushort4*)((u16*)Cp + c * (long)M + r) = o;
          } else if (MODE == 2) {
            const long b2 = r >> 11;
            const long i = r & 2047;
            const float bc = bias[c];
            ushort4 o;
            o.x = f2bf(v[4 * q + 0] + bc); o.y = f2bf(v[4 * q + 1] + bc);
            o.z = f2bf(v[4 * q + 2] + bc); o.w = f2bf(v[4 * q + 3] + bc);
            *(ushort4*)((u16*)Cp + b2 * 2097152L + c * 2048L + i) = o;
          } else {
            float4 bb = *(const float4*)(bias + r);
            float4 o;
            o.x = v[4 * q + 0] + bb.x; o.y = v[4 * q + 1] + bb.y;
            o.z = v[4 * q + 2] + bb.z; o.w = v[4 * q + 3] + bb.w;
            *(float4*)((float*)Cp + c * (long)M + r) = o;
          }
        }
      }
    }
  }
#undef LDA32
#undef LDB32
#undef RDA
#undef RDB
#undef MFMAQ
#undef GTILE
}

// ---------- launcher ----------
extern "C" void kernel_launch(void* const* d_in, const int* in_sizes, int n_in,
                              void* d_out, int out_size, void* d_ws, size_t ws_size,
                              hipStream_t stream) {
  const float* img  = (const float*)d_in[0];
  const float* refp = (const float*)d_in[1];
  const float* pose = (const float*)d_in[2];
  const float* gam  = (const float*)d_in[3];
  const float* bet  = (const float*)d_in[4];
  const float* Wq = (const float*)d_in[5];
  const float* bq = (const float*)d_in[6];
  const float* Wk = (const float*)d_in[7];
  const float* bk = (const float*)d_in[8];
  const float* Wv = (const float*)d_in[9];
  const float* bv = (const float*)d_in[10];
  const float* Wo = (const float*)d_in[11];
  const float* bo = (const float*)d_in[12];

  char* ws = (char*)d_ws;
  const size_t MB = 1u << 20;
  u16* Wq_b = (u16*)(ws + 0 * MB);
  u16* Wk_b = (u16*)(ws + 2 * MB);
  u16* Wv_b = (u16*)(ws + 4 * MB);
  u16* Wo_b = (u16*)(ws + 6 * MB);           // 1.5 MB
  float* rowsum = (float*)(ws + 7 * MB + 512 * 1024);  // 64 KB
  u16* bufA = (u16*)(ws + 8 * MB);    // ref_n, later K-proj
  u16* bufB = (u16*)(ws + 40 * MB);   // pose_n
  u16* bufC = (u16*)(ws + 72 * MB);   // img_n
  u16* bufD = (u16*)(ws + 104 * MB);  // Q, later X
  u16* bufE = (u16*)(ws + 136 * MB);  // V^T
  u16* bufL = (u16*)(ws + 168 * MB);  // exp(logits) bf16 (64 MB)

  const int LDSB = 131072;
  hipFuncSetAttribute((const void*)gemm256<0>, hipFuncAttributeMaxDynamicSharedMemorySize, LDSB);
  hipFuncSetAttribute((const void*)gemm256<1>, hipFuncAttributeMaxDynamicSharedMemorySize, LDSB);
  hipFuncSetAttribute((const void*)gemm256<2>, hipFuncAttributeMaxDynamicSharedMemorySize, LDSB);
  hipFuncSetAttribute((const void*)gemm256<3>, hipFuncAttributeMaxDynamicSharedMemorySize, LDSB);
  hipFuncSetAttribute((const void*)gemm256<4>, hipFuncAttributeMaxDynamicSharedMemorySize, LDSB);

  // zero row-sum accumulator (graph-capture safe)
  hipMemsetAsync(rowsum, 0, 8 * 2048 * sizeof(float), stream);

  // all weights to bf16 (one launch)
  cvt_all<<<3840, 256, 0, stream>>>(Wq, Wk, Wv, Wo, Wq_b, Wk_b, Wv_b, Wo_b);

  // all three layernorms (one launch)
  ln3<<<dim3(16384, 3), 256, 0, stream>>>(refp, pose, img, gam, bet, bufA, bufB, bufC);

  // Q[i,e] = ref_n @ Wq^T + bq  (swapped: A=Wq, B=ref_n; ty fast, g=4)
  gemm256<0><<<256, 512, LDSB, stream>>>(Wq_b, bufA, bq, bufD, nullptr, nullptr, nullptr,
                                         1024, 16384, 1024, 0, 0, 0, 1.f,
                                         64, 4, 4, 0);
  // K[i,e] = pose_n @ Wk^T + bk  (overwrites bufA; ref_n dead)
  gemm256<0><<<256, 512, LDSB, stream>>>(Wk_b, bufB, bk, bufA, nullptr, nullptr, nullptr,
                                         1024, 16384, 1024, 0, 0, 0, 1.f,
                                         64, 4, 4, 0);
  // V^T[b][d][key] = (img_n @ Wv^T + bv)^T  (direct orientation; tx fast, g=4)
  gemm256<2><<<256, 512, LDSB, stream>>>(bufC, Wv_b, bv, bufE, nullptr, nullptr, nullptr,
                                         16384, 1024, 1024, 0, 0, 0, 1.f,
                                         4, 64, 4, 1);
  // P[i,j] = exp((Q@K^T)/32)  (swapped: A=K, B=Q); row-sums via atomics
  gemm256<1><<<512, 512, LDSB, stream>>>(bufA, bufD, nullptr, bufL, nullptr, nullptr, rowsum,
                                         2048, 2048, 1024,
                                         2048L * 1024, 2048L * 1024, 2048L * 2048,
                                         0.03125f, 8, 8, 4, 0);
  // X[i,d] = (P @ V)/rowsum + pose_n + img_n  (swapped: A=V^T, B=P)
  gemm256<3><<<256, 512, LDSB, stream>>>(bufE, bufL, nullptr, bufD, bufB, bufC, rowsum,
                                         1024, 2048, 2048,
                                         1024L * 2048, 2048L * 2048, 2048L * 1024, 1.f,
                                         8, 4, 4, 0);
  // out[i,o] = X @ Wo^T + bo  (swapped: A=Wo, B=X; ty fast, g=3)
  gemm256<4><<<192, 512, LDSB, stream>>>(Wo_b, bufD, bo, d_out, nullptr, nullptr, nullptr,
                                         768, 16384, 1024, 0, 0, 0, 1.f,
                                         64, 3, 3, 0);
}

// Round 7
// 383.508 us; speedup vs baseline: 1.1365x; 1.1365x over previous
//
#include <hip/hip_runtime.h>
#include <hip/hip_bf16.h>

typedef __attribute__((ext_vector_type(8))) short short8;
typedef __attribute__((ext_vector_type(4))) float f32x4;
typedef unsigned short u16;

// ---------- helpers ----------
__device__ __forceinline__ u16 f2bf(float f) {
  union { float f; unsigned u; } v; v.f = f;
  unsigned r = v.u + 0x7fffu + ((v.u >> 16) & 1u);
  return (u16)(r >> 16);
}
__device__ __forceinline__ float bf2f(u16 u) {
  union { unsigned u; float f; } v; v.u = ((unsigned)u) << 16;
  return v.f;
}
__device__ __forceinline__ void gload16(const void* g, void* l) {
  __builtin_amdgcn_global_load_lds(
      (const __attribute__((address_space(1))) unsigned*)g,
      (__attribute__((address_space(3))) unsigned*)l, 16, 0, 0);
}

#define FENCE asm volatile("" ::: "memory")
#define SB0 __builtin_amdgcn_sched_barrier(0)
#define BAR do { FENCE; __builtin_amdgcn_s_barrier(); FENCE; } while (0)

// ---------- fused LayerNorm x3 + weight cvt + rowsum zero (one launch) ----------
// blockIdx.y in {0,1,2}: LN of refp/pose/img -> bf16.
// blockIdx.y == 3: blocks [0,3840): fp32->bf16 weight convert (Wq,Wk,Wv,Wo);
//                  blocks [3840,3848): zero rowsum (8*2048 floats).
__global__ __launch_bounds__(256)
void ln_cvt(const float* __restrict__ refp, const float* __restrict__ pose,
            const float* __restrict__ img, const float* __restrict__ gamma,
            const float* __restrict__ beta, u16* __restrict__ oA,
            u16* __restrict__ oB, u16* __restrict__ oC,
            const float* __restrict__ Wq, const float* __restrict__ Wk,
            const float* __restrict__ Wv, const float* __restrict__ Wo,
            u16* __restrict__ oq, u16* __restrict__ ok, u16* __restrict__ ov,
            u16* __restrict__ oo, float* __restrict__ rsum) {
  const int tid = threadIdx.x;
  if (blockIdx.y == 3) {
    const int b = blockIdx.x;
    if (b < 3840) {
      int i = b * 256 + tid;                 // float4 index; total 983040
      const int W1 = 262144;                 // 1024*1024/4
      const float* src;
      u16* dst;
      int j;
      if (i < W1) { src = Wq; dst = oq; j = i; }
      else if (i < 2 * W1) { src = Wk; dst = ok; j = i - W1; }
      else if (i < 3 * W1) { src = Wv; dst = ov; j = i - 2 * W1; }
      else { src = Wo; dst = oo; j = i - 3 * W1; }
      float4 x = ((const float4*)src)[j];
      ushort4 o;
      o.x = f2bf(x.x); o.y = f2bf(x.y); o.z = f2bf(x.z); o.w = f2bf(x.w);
      ((ushort4*)dst)[j] = o;
    } else if (b < 3848) {
      // zero rowsum: 16384 floats total = 8 blocks * 256 threads * 8 floats
      float4 z = {0.f, 0.f, 0.f, 0.f};
      float* p = rsum + (long)(b - 3840) * 2048 + tid * 8;
      *(float4*)p = z;
      *(float4*)(p + 4) = z;
    }
    return;
  }
  const int row = blockIdx.x;
  const float* X = (blockIdx.y == 0) ? refp : (blockIdx.y == 1) ? pose : img;
  u16* Y = (blockIdx.y == 0) ? oA : (blockIdx.y == 1) ? oB : oC;
  const long base = (long)row * 1024 + tid * 4;
  float4 x = *(const float4*)(X + base);
  float s = x.x + x.y + x.z + x.w;
  float q = x.x * x.x + x.y * x.y + x.z * x.z + x.w * x.w;
#pragma unroll
  for (int o = 32; o > 0; o >>= 1) {
    s += __shfl_xor(s, o);
    q += __shfl_xor(q, o);
  }
  __shared__ float rs[4], rq[4];
  if ((tid & 63) == 0) { rs[tid >> 6] = s; rq[tid >> 6] = q; }
  __syncthreads();
  s = rs[0] + rs[1] + rs[2] + rs[3];
  q = rq[0] + rq[1] + rq[2] + rq[3];
  float mu = s * (1.f / 1024.f);
  float var = q * (1.f / 1024.f) - mu * mu;
  float rstd = rsqrtf(var + 1e-5f);
  float4 g = *(const float4*)(gamma + tid * 4);
  float4 b = *(const float4*)(beta + tid * 4);
  ushort4 o4;
  o4.x = f2bf((x.x - mu) * rstd * g.x + b.x);
  o4.y = f2bf((x.y - mu) * rstd * g.y + b.y);
  o4.z = f2bf((x.z - mu) * rstd * g.z + b.z);
  o4.w = f2bf((x.w - mu) * rstd * g.w + b.w);
  *(ushort4*)(Y + base) = o4;
}

// ---------- 256x256 GEMM, 2-tile-unrolled quadrant schedule, transpose-store ----------
// C' = A·B^T, A [M,K], B [N,K], K-contiguous. Output transposed: out[c, r].
// XCD-chunked 1D mapping.
// MODE 0: bf16 out[c*M + r] = acc + bias[r]
// MODE 1: bf16 out[cb + c*M + r] = exp(acc*scale); atomicAdd rsum[tz*2048+c]
// MODE 2: (direct orientation) bf16 out[b2*2^21 + c*2048 + (r&2047)] = acc + bias[c]
// MODE 3: bf16 out[cb + c*M + r] = acc / rsum[tz*2048+c] + R1 + R2
// MODE 4: fp32 out[c*M + r] = acc + bias[r]
template <int MODE>
__global__ __launch_bounds__(512, 2)
void gemm256(const u16* __restrict__ A, const u16* __restrict__ B,
             const float* __restrict__ bias, void* __restrict__ Cp,
             const u16* __restrict__ R1, const u16* __restrict__ R2,
             float* __restrict__ rsum,
             int M, int N, int K, long sA, long sB, long sC, float scale,
             int ntx, int nty, int g, int fdim) {
  extern __shared__ char lds[];
  // ---- logical tile mapping ----
  const int nwg = gridDim.x;
  const int chunk = nwg >> 3;
  int l = (blockIdx.x & 7) * chunk + (blockIdx.x >> 3);
  const int per = ntx * nty;
  const int tz = l / per;
  int li = l - tz * per;
  const int ns = fdim ? nty : ntx;
  const int fi = li % g;
  const int s_ = (li / g) % ns;
  const int fB2 = li / (g * ns);
  const int f = fB2 * g + fi;
  const int tx = fdim ? f : s_;
  const int ty = fdim ? s_ : f;

  const u16* Ab = A + (long)tz * sA;
  const u16* Bb = B + (long)tz * sB;
  const long cb = (long)tz * sC;

  const int tid = threadIdx.x;
  const int lane = tid & 63;
  const int wid = tid >> 6;
  const int wr = wid >> 2;   // 0..1
  const int wc = wid & 3;    // 0..3
  const long rowBase = (long)ty * 256;
  const long colBase = (long)tx * 256;
  const int fr = lane & 15;
  const int fk = lane >> 4;  // 0..3
  const int nt = K >> 6;

  // loop-invariant LDS read offsets (swizzled)
  const int ch0 = (fk ^ (fr & 7)) * 16;
  const int ch1 = ((4 + fk) ^ (fr & 7)) * 16;
  const int aB = (wr * 128 + fr) * 128;          // + m*2048 (+buf*65536)
  const int bB = 32768 + (wc * 64 + fr) * 128;   // + n*2048 (+buf*65536)

#define LDA(BUF, m, k2) \
  (*(const short8*)(lds + (BUF) * 65536 + aB + (m) * 2048 + ((k2) ? ch1 : ch0)))
#define LDB(BUF, n, k2) \
  (*(const short8*)(lds + (BUF) * 65536 + bB + (n) * 2048 + ((k2) ? ch1 : ch0)))

  // stage half-tile h (128 rows x 64 cols) of A (bOff=0) or B (bOff=32768) into buf
  auto stage = [&](const u16* __restrict__ gb, long rcBase, int t, int h, int bOff, int buf) {
    char* base = lds + buf * 65536 + bOff + h * 16384;
    const long kk = (long)t << 6;
#pragma unroll
    for (int i = 0; i < 2; ++i) {
      const int o = i * 8192 + tid * 16;   // linear byte in half-tile
      const int row = o >> 7;              // 0..127
      const int cs = (o >> 4) & 7;         // 16B chunk slot
      const long gr = rcBase + h * 128 + row;
      const long gk = kk + (long)((cs ^ (row & 7)) << 3);
      gload16(gb + gr * (long)K + gk, base + o);
    }
  };

  f32x4 acc[8][4] = {};
  short8 ar[4][2];
  short8 br[4][2];

#define RDA(BUF, M0)                                         \
  _Pragma("unroll") for (int mm = 0; mm < 4; ++mm) {         \
    ar[mm][0] = LDA(BUF, (M0) + mm, 0);                      \
    ar[mm][1] = LDA(BUF, (M0) + mm, 1);                      \
  }
#define RDB2(BUF, N0)                                        \
  _Pragma("unroll") for (int nn = 0; nn < 2; ++nn) {         \
    br[(N0) + nn][0] = LDB(BUF, (N0) + nn, 0);               \
    br[(N0) + nn][1] = LDB(BUF, (N0) + nn, 1);               \
  }
#define MFMAQ(M0, N0)                                                                \
  __builtin_amdgcn_s_setprio(1);                                                     \
  _Pragma("unroll") for (int k2 = 0; k2 < 2; ++k2)                                   \
  _Pragma("unroll") for (int nn = 0; nn < 2; ++nn)                                   \
  _Pragma("unroll") for (int mm = 0; mm < 4; ++mm)                                   \
      acc[(M0) + mm][(N0) + nn] = __builtin_amdgcn_mfma_f32_16x16x32_bf16(           \
          ar[mm][k2], br[(N0) + nn][k2], acc[(M0) + mm][(N0) + nn], 0, 0, 0);        \
  __builtin_amdgcn_s_setprio(0);

#define GTILE(T, BUF)                                                      \
  do {                                                                     \
    RDA(BUF, 0);                                                           \
    RDB2(BUF, 0);                                                          \
    if ((T) + 1 < nt) stage(Ab, rowBase, (T) + 1, 1, 0, (BUF) ^ 1);        \
    BAR; SB0; MFMAQ(0, 0); SB0; BAR;                                       \
    RDB2(BUF, 2);                                                          \
    BAR; SB0; MFMAQ(0, 2); SB0; BAR;                                       \
    RDA(BUF, 4);                                                           \
    if ((T) + 2 < nt) stage(Bb, colBase, (T) + 2, 0, 32768, BUF);          \
    BAR; SB0; MFMAQ(4, 0); SB0; BAR;                                       \
    if ((T) + 2 < nt) {                                                    \
      stage(Bb, colBase, (T) + 2, 1, 32768, BUF);                          \
      stage(Ab, rowBase, (T) + 2, 0, 0, BUF);                              \
      asm volatile("s_waitcnt vmcnt(6)" ::: "memory");                     \
    } else {                                                               \
      asm volatile("s_waitcnt vmcnt(0)" ::: "memory");                     \
    }                                                                      \
    BAR; SB0; MFMAQ(4, 2); SB0; BAR;                                       \
  } while (0)

  // prologue: tile0 full into buf0; tile1 (A h0, B h0, B h1) into buf1
  stage(Ab, rowBase, 0, 0, 0, 0);
  stage(Ab, rowBase, 0, 1, 0, 0);
  stage(Bb, colBase, 0, 0, 32768, 0);
  stage(Bb, colBase, 0, 1, 32768, 0);
  if (nt > 1) {
    stage(Ab, rowBase, 1, 0, 0, 1);
    stage(Bb, colBase, 1, 0, 32768, 1);
    stage(Bb, colBase, 1, 1, 32768, 1);
    asm volatile("s_waitcnt vmcnt(6)" ::: "memory");
  } else {
    asm volatile("s_waitcnt vmcnt(0)" ::: "memory");
  }
  BAR;

  for (int tt = 0; tt < nt; tt += 2) {
    GTILE(tt, 0);
    GTILE(tt + 1, 1);
  }

  // ---------- epilogue: transpose-store, per-lane 4 consecutive r ----------
  if (MODE == 1) {
#pragma unroll
    for (int n = 0; n < 4; ++n) {
      const long c = colBase + wc * 64 + n * 16 + fr;
      float ps = 0.f;
#pragma unroll
      for (int m = 0; m < 8; ++m) {
        const long r = rowBase + wr * 128 + m * 16 + fk * 4;
        f32x4 v = acc[m][n];
        float e0 = __expf(v[0] * scale), e1 = __expf(v[1] * scale);
        float e2 = __expf(v[2] * scale), e3 = __expf(v[3] * scale);
        ps += (e0 + e1) + (e2 + e3);
        ushort4 o;
        o.x = f2bf(e0); o.y = f2bf(e1); o.z = f2bf(e2); o.w = f2bf(e3);
        *(ushort4*)((u16*)Cp + cb + c * (long)M + r) = o;
      }
      ps += __shfl_xor(ps, 16);
      ps += __shfl_xor(ps, 32);
      if (lane < 16) atomicAdd(&rsum[(long)tz * 2048 + c], ps);
    }
  } else if (MODE == 3) {
#pragma unroll
    for (int n = 0; n < 4; ++n) {
      const long c = colBase + wc * 64 + n * 16 + fr;
      const float inv = 1.f / rsum[(long)tz * 2048 + c];
#pragma unroll
      for (int m = 0; m < 8; ++m) {
        const long r = rowBase + wr * 128 + m * 16 + fk * 4;
        const long idx = cb + c * (long)M + r;
        f32x4 v = acc[m][n];
        ushort4 r1 = *(const ushort4*)(R1 + idx);
        ushort4 r2 = *(const ushort4*)(R2 + idx);
        ushort4 o;
        o.x = f2bf(v[0] * inv + bf2f(r1.x) + bf2f(r2.x));
        o.y = f2bf(v[1] * inv + bf2f(r1.y) + bf2f(r2.y));
        o.z = f2bf(v[2] * inv + bf2f(r1.z) + bf2f(r2.z));
        o.w = f2bf(v[3] * inv + bf2f(r1.w) + bf2f(r2.w));
        *(ushort4*)((u16*)Cp + idx) = o;
      }
    }
  } else {
#pragma unroll
    for (int m = 0; m < 8; ++m) {
#pragma unroll
      for (int n = 0; n < 4; ++n) {
        const long r = rowBase + wr * 128 + m * 16 + fk * 4;
        const long c = colBase + wc * 64 + n * 16 + fr;
        f32x4 v = acc[m][n];
        if (MODE == 0) {
          float4 bb = *(const float4*)(bias + r);
          ushort4 o;
          o.x = f2bf(v[0] + bb.x); o.y = f2bf(v[1] + bb.y);
          o.z = f2bf(v[2] + bb.z); o.w = f2bf(v[3] + bb.w);
          *(ushort4*)((u16*)Cp + c * (long)M + r) = o;
        } else if (MODE == 2) {
          const long b2 = r >> 11;
          const long i = r & 2047;
          const float bc = bias[c];
          ushort4 o;
          o.x = f2bf(v[0] + bc); o.y = f2bf(v[1] + bc);
          o.z = f2bf(v[2] + bc); o.w = f2bf(v[3] + bc);
          *(ushort4*)((u16*)Cp + b2 * 2097152L + c * 2048L + i) = o;
        } else {
          float4 bb = *(const float4*)(bias + r);
          float4 o;
          o.x = v[0] + bb.x; o.y = v[1] + bb.y; o.z = v[2] + bb.z; o.w = v[3] + bb.w;
          *(float4*)((float*)Cp + c * (long)M + r) = o;
        }
      }
    }
  }
#undef LDA
#undef LDB
#undef RDA
#undef RDB2
#undef MFMAQ
#undef GTILE
}

// ---------- launcher ----------
extern "C" void kernel_launch(void* const* d_in, const int* in_sizes, int n_in,
                              void* d_out, int out_size, void* d_ws, size_t ws_size,
                              hipStream_t stream) {
  const float* img  = (const float*)d_in[0];
  const float* refp = (const float*)d_in[1];
  const float* pose = (const float*)d_in[2];
  const float* gam  = (const float*)d_in[3];
  const float* bet  = (const float*)d_in[4];
  const float* Wq = (const float*)d_in[5];
  const float* bq = (const float*)d_in[6];
  const float* Wk = (const float*)d_in[7];
  const float* bk = (const float*)d_in[8];
  const float* Wv = (const float*)d_in[9];
  const float* bv = (const float*)d_in[10];
  const float* Wo = (const float*)d_in[11];
  const float* bo = (const float*)d_in[12];

  char* ws = (char*)d_ws;
  const size_t MB = 1u << 20;
  u16* Wq_b = (u16*)(ws + 0 * MB);
  u16* Wk_b = (u16*)(ws + 2 * MB);
  u16* Wv_b = (u16*)(ws + 4 * MB);
  u16* Wo_b = (u16*)(ws + 6 * MB);           // 1.5 MB
  float* rowsum = (float*)(ws + 7 * MB + 512 * 1024);  // 64 KB
  u16* bufA = (u16*)(ws + 8 * MB);    // ref_n, later K-proj
  u16* bufB = (u16*)(ws + 40 * MB);   // pose_n
  u16* bufC = (u16*)(ws + 72 * MB);   // img_n
  u16* bufD = (u16*)(ws + 104 * MB);  // Q, later X
  u16* bufE = (u16*)(ws + 136 * MB);  // V^T
  u16* bufL = (u16*)(ws + 168 * MB);  // exp(logits) bf16 (64 MB)

  const int LDSB = 131072;
  hipFuncSetAttribute((const void*)gemm256<0>, hipFuncAttributeMaxDynamicSharedMemorySize, LDSB);
  hipFuncSetAttribute((const void*)gemm256<1>, hipFuncAttributeMaxDynamicSharedMemorySize, LDSB);
  hipFuncSetAttribute((const void*)gemm256<2>, hipFuncAttributeMaxDynamicSharedMemorySize, LDSB);
  hipFuncSetAttribute((const void*)gemm256<3>, hipFuncAttributeMaxDynamicSharedMemorySize, LDSB);
  hipFuncSetAttribute((const void*)gemm256<4>, hipFuncAttributeMaxDynamicSharedMemorySize, LDSB);

  // layernorms x3 + weight cvt + rowsum zero (one launch)
  ln_cvt<<<dim3(16384, 4), 256, 0, stream>>>(refp, pose, img, gam, bet,
                                             bufA, bufB, bufC,
                                             Wq, Wk, Wv, Wo,
                                             Wq_b, Wk_b, Wv_b, Wo_b, rowsum);

  // Q[i,e] = ref_n @ Wq^T + bq  (swapped: A=Wq, B=ref_n; ty fast, g=4)
  gemm256<0><<<256, 512, LDSB, stream>>>(Wq_b, bufA, bq, bufD, nullptr, nullptr, nullptr,
                                         1024, 16384, 1024, 0, 0, 0, 1.f,
                                         64, 4, 4, 0);
  // K[i,e] = pose_n @ Wk^T + bk  (overwrites bufA; ref_n dead)
  gemm256<0><<<256, 512, LDSB, stream>>>(Wk_b, bufB, bk, bufA, nullptr, nullptr, nullptr,
                                         1024, 16384, 1024, 0, 0, 0, 1.f,
                                         64, 4, 4, 0);
  // V^T[b][d][key] = (img_n @ Wv^T + bv)^T  (direct orientation; tx fast, g=4)
  gemm256<2><<<256, 512, LDSB, stream>>>(bufC, Wv_b, bv, bufE, nullptr, nullptr, nullptr,
                                         16384, 1024, 1024, 0, 0, 0, 1.f,
                                         4, 64, 4, 1);
  // P[i,j] = exp((Q@K^T)/32)  (swapped: A=K, B=Q); row-sums via atomics
  gemm256<1><<<512, 512, LDSB, stream>>>(bufA, bufD, nullptr, bufL, nullptr, nullptr, rowsum,
                                         2048, 2048, 1024,
                                         2048L * 1024, 2048L * 1024, 2048L * 2048,
                                         0.03125f, 8, 8, 4, 0);
  // X[i,d] = (P @ V)/rowsum + pose_n + img_n  (swapped: A=V^T, B=P)
  gemm256<3><<<256, 512, LDSB, stream>>>(bufE, bufL, nullptr, bufD, bufB, bufC, rowsum,
                                         1024, 2048, 2048,
                                         1024L * 2048, 2048L * 2048, 2048L * 1024, 1.f,
                                         8, 4, 4, 0);
  // out[i,o] = X @ Wo^T + bo  (swapped: A=Wo, B=X; ty fast, g=3)
  gemm256<4><<<192, 512, LDSB, stream>>>(Wo_b, bufD, bo, d_out, nullptr, nullptr, nullptr,
                                         768, 16384, 1024, 0, 0, 0, 1.f,
                                         64, 3, 3, 0);
}

// Round 8
// 372.481 us; speedup vs baseline: 1.1702x; 1.0296x over previous
//
#include <hip/hip_runtime.h>
#include <hip/hip_bf16.h>

typedef __attribute__((ext_vector_type(8))) short short8;
typedef __attribute__((ext_vector_type(4))) float f32x4;
typedef unsigned short u16;

// ---------- helpers ----------
__device__ __forceinline__ u16 f2bf(float f) {
  union { float f; unsigned u; } v; v.f = f;
  unsigned r = v.u + 0x7fffu + ((v.u >> 16) & 1u);
  return (u16)(r >> 16);
}
__device__ __forceinline__ float bf2f(u16 u) {
  union { unsigned u; float f; } v; v.u = ((unsigned)u) << 16;
  return v.f;
}
__device__ __forceinline__ void gload16(const void* g, void* l) {
  __builtin_amdgcn_global_load_lds(
      (const __attribute__((address_space(1))) unsigned*)g,
      (__attribute__((address_space(3))) unsigned*)l, 16, 0, 0);
}

#define FENCE asm volatile("" ::: "memory")
#define SB0 __builtin_amdgcn_sched_barrier(0)
#define BAR do { FENCE; __builtin_amdgcn_s_barrier(); FENCE; } while (0)

// ---------- fused LayerNorm x3 + weight cvt + rowsum zero (one launch) ----------
__global__ __launch_bounds__(256)
void ln_cvt(const float* __restrict__ refp, const float* __restrict__ pose,
            const float* __restrict__ img, const float* __restrict__ gamma,
            const float* __restrict__ beta, u16* __restrict__ oA,
            u16* __restrict__ oB, u16* __restrict__ oC,
            const float* __restrict__ Wq, const float* __restrict__ Wk,
            const float* __restrict__ Wv, const float* __restrict__ Wo,
            u16* __restrict__ oq, u16* __restrict__ ok, u16* __restrict__ ov,
            u16* __restrict__ oo, float* __restrict__ rsum) {
  const int tid = threadIdx.x;
  if (blockIdx.y == 3) {
    const int b = blockIdx.x;
    if (b < 3840) {
      int i = b * 256 + tid;                 // float4 index; total 983040
      const int W1 = 262144;                 // 1024*1024/4
      const float* src;
      u16* dst;
      int j;
      if (i < W1) { src = Wq; dst = oq; j = i; }
      else if (i < 2 * W1) { src = Wk; dst = ok; j = i - W1; }
      else if (i < 3 * W1) { src = Wv; dst = ov; j = i - 2 * W1; }
      else { src = Wo; dst = oo; j = i - 3 * W1; }
      float4 x = ((const float4*)src)[j];
      ushort4 o;
      o.x = f2bf(x.x); o.y = f2bf(x.y); o.z = f2bf(x.z); o.w = f2bf(x.w);
      ((ushort4*)dst)[j] = o;
    } else if (b < 3848) {
      float4 z = {0.f, 0.f, 0.f, 0.f};
      float* p = rsum + (long)(b - 3840) * 2048 + tid * 8;
      *(float4*)p = z;
      *(float4*)(p + 4) = z;
    }
    return;
  }
  const int row = blockIdx.x;
  const float* X = (blockIdx.y == 0) ? refp : (blockIdx.y == 1) ? pose : img;
  u16* Y = (blockIdx.y == 0) ? oA : (blockIdx.y == 1) ? oB : oC;
  const long base = (long)row * 1024 + tid * 4;
  float4 x = *(const float4*)(X + base);
  float s = x.x + x.y + x.z + x.w;
  float q = x.x * x.x + x.y * x.y + x.z * x.z + x.w * x.w;
#pragma unroll
  for (int o = 32; o > 0; o >>= 1) {
    s += __shfl_xor(s, o);
    q += __shfl_xor(q, o);
  }
  __shared__ float rs[4], rq[4];
  if ((tid & 63) == 0) { rs[tid >> 6] = s; rq[tid >> 6] = q; }
  __syncthreads();
  s = rs[0] + rs[1] + rs[2] + rs[3];
  q = rq[0] + rq[1] + rq[2] + rq[3];
  float mu = s * (1.f / 1024.f);
  float var = q * (1.f / 1024.f) - mu * mu;
  float rstd = rsqrtf(var + 1e-5f);
  float4 g = *(const float4*)(gamma + tid * 4);
  float4 b = *(const float4*)(beta + tid * 4);
  ushort4 o4;
  o4.x = f2bf((x.x - mu) * rstd * g.x + b.x);
  o4.y = f2bf((x.y - mu) * rstd * g.y + b.y);
  o4.z = f2bf((x.z - mu) * rstd * g.z + b.z);
  o4.w = f2bf((x.w - mu) * rstd * g.w + b.w);
  *(ushort4*)(Y + base) = o4;
}

// ---------- 256x256 GEMM body, 2-tile-unrolled quadrant schedule, transpose-store ----
// C' = A·B^T, A [M,K], B [N,K], K-contiguous. Output transposed: out[c, r].
// XCD-chunked 1D mapping on (bid, nwg).
// MODE 0: bf16 out[c*M + r] = acc + bias[r]
// MODE 1: bf16 out[cb + c*M + r] = exp(acc*scale); atomicAdd rsum[tz*2048+c]
// MODE 2: (direct orientation) bf16 out[b2*2^21 + c*2048 + (r&2047)] = acc + bias[c]
// MODE 3: bf16 out[cb + c*M + r] = acc / rsum[tz*2048+c] + R1 + R2
// MODE 4: fp32 out[c*M + r] = acc + bias[r]
template <int MODE>
__device__ __forceinline__
void gemm_body(const u16* __restrict__ A, const u16* __restrict__ B,
               const float* __restrict__ bias, void* __restrict__ Cp,
               const u16* __restrict__ R1, const u16* __restrict__ R2,
               float* __restrict__ rsum,
               int M, int N, int K, long sA, long sB, long sC, float scale,
               int ntx, int nty, int g, int fdim, int bid, int nwg, char* lds) {
  // ---- logical tile mapping ----
  const int chunk = nwg >> 3;
  int l = (bid & 7) * chunk + (bid >> 3);
  const int per = ntx * nty;
  const int tz = l / per;
  int li = l - tz * per;
  const int ns = fdim ? nty : ntx;
  const int fi = li % g;
  const int s_ = (li / g) % ns;
  const int fB2 = li / (g * ns);
  const int f = fB2 * g + fi;
  const int tx = fdim ? f : s_;
  const int ty = fdim ? s_ : f;

  const u16* Ab = A + (long)tz * sA;
  const u16* Bb = B + (long)tz * sB;
  const long cb = (long)tz * sC;

  const int tid = threadIdx.x;
  const int lane = tid & 63;
  const int wid = tid >> 6;
  const int wr = wid >> 2;   // 0..1
  const int wc = wid & 3;    // 0..3
  const long rowBase = (long)ty * 256;
  const long colBase = (long)tx * 256;
  const int fr = lane & 15;
  const int fk = lane >> 4;  // 0..3
  const int nt = K >> 6;

  // loop-invariant LDS read offsets (swizzled)
  const int ch0 = (fk ^ (fr & 7)) * 16;
  const int ch1 = ((4 + fk) ^ (fr & 7)) * 16;
  const int aB = (wr * 128 + fr) * 128;          // + m*2048 (+buf*65536)
  const int bB = 32768 + (wc * 64 + fr) * 128;   // + n*2048 (+buf*65536)

#define LDA(BUF, m, k2) \
  (*(const short8*)(lds + (BUF) * 65536 + aB + (m) * 2048 + ((k2) ? ch1 : ch0)))
#define LDB(BUF, n, k2) \
  (*(const short8*)(lds + (BUF) * 65536 + bB + (n) * 2048 + ((k2) ? ch1 : ch0)))

  // stage half-tile h (128 rows x 64 cols) of A (bOff=0) or B (bOff=32768) into buf
  auto stage = [&](const u16* __restrict__ gb, long rcBase, int t, int h, int bOff, int buf) {
    char* base = lds + buf * 65536 + bOff + h * 16384;
    const long kk = (long)t << 6;
#pragma unroll
    for (int i = 0; i < 2; ++i) {
      const int o = i * 8192 + tid * 16;   // linear byte in half-tile
      const int row = o >> 7;              // 0..127
      const int cs = (o >> 4) & 7;         // 16B chunk slot
      const long gr = rcBase + h * 128 + row;
      const long gk = kk + (long)((cs ^ (row & 7)) << 3);
      gload16(gb + gr * (long)K + gk, base + o);
    }
  };

  f32x4 acc[8][4] = {};
  short8 ar[4][2];
  short8 br[4][2];

#define RDA(BUF, M0)                                         \
  _Pragma("unroll") for (int mm = 0; mm < 4; ++mm) {         \
    ar[mm][0] = LDA(BUF, (M0) + mm, 0);                      \
    ar[mm][1] = LDA(BUF, (M0) + mm, 1);                      \
  }
#define RDB2(BUF, N0)                                        \
  _Pragma("unroll") for (int nn = 0; nn < 2; ++nn) {         \
    br[(N0) + nn][0] = LDB(BUF, (N0) + nn, 0);               \
    br[(N0) + nn][1] = LDB(BUF, (N0) + nn, 1);               \
  }
#define MFMAQ(M0, N0)                                                                \
  __builtin_amdgcn_s_setprio(1);                                                     \
  _Pragma("unroll") for (int k2 = 0; k2 < 2; ++k2)                                   \
  _Pragma("unroll") for (int nn = 0; nn < 2; ++nn)                                   \
  _Pragma("unroll") for (int mm = 0; mm < 4; ++mm)                                   \
      acc[(M0) + mm][(N0) + nn] = __builtin_amdgcn_mfma_f32_16x16x32_bf16(           \
          ar[mm][k2], br[(N0) + nn][k2], acc[(M0) + mm][(N0) + nn], 0, 0, 0);        \
  __builtin_amdgcn_s_setprio(0);

#define GTILE(T, BUF)                                                      \
  do {                                                                     \
    RDA(BUF, 0);                                                           \
    RDB2(BUF, 0);                                                          \
    if ((T) + 1 < nt) stage(Ab, rowBase, (T) + 1, 1, 0, (BUF) ^ 1);        \
    BAR; SB0; MFMAQ(0, 0); SB0; BAR;                                       \
    RDB2(BUF, 2);                                                          \
    BAR; SB0; MFMAQ(0, 2); SB0; BAR;                                       \
    RDA(BUF, 4);                                                           \
    if ((T) + 2 < nt) stage(Bb, colBase, (T) + 2, 0, 32768, BUF);          \
    BAR; SB0; MFMAQ(4, 0); SB0; BAR;                                       \
    if ((T) + 2 < nt) {                                                    \
      stage(Bb, colBase, (T) + 2, 1, 32768, BUF);                          \
      stage(Ab, rowBase, (T) + 2, 0, 0, BUF);                              \
      asm volatile("s_waitcnt vmcnt(6)" ::: "memory");                     \
    } else {                                                               \
      asm volatile("s_waitcnt vmcnt(0)" ::: "memory");                     \
    }                                                                      \
    BAR; SB0; MFMAQ(4, 2); SB0; BAR;                                       \
  } while (0)

  // prologue: tile0 full into buf0; tile1 (A h0, B h0, B h1) into buf1
  stage(Ab, rowBase, 0, 0, 0, 0);
  stage(Ab, rowBase, 0, 1, 0, 0);
  stage(Bb, colBase, 0, 0, 32768, 0);
  stage(Bb, colBase, 0, 1, 32768, 0);
  if (nt > 1) {
    stage(Ab, rowBase, 1, 0, 0, 1);
    stage(Bb, colBase, 1, 0, 32768, 1);
    stage(Bb, colBase, 1, 1, 32768, 1);
    asm volatile("s_waitcnt vmcnt(6)" ::: "memory");
  } else {
    asm volatile("s_waitcnt vmcnt(0)" ::: "memory");
  }
  BAR;

  for (int tt = 0; tt < nt; tt += 2) {
    GTILE(tt, 0);
    GTILE(tt + 1, 1);
  }

  // ---------- epilogue: transpose-store, per-lane 4 consecutive r ----------
  if (MODE == 1) {
#pragma unroll
    for (int n = 0; n < 4; ++n) {
      const long c = colBase + wc * 64 + n * 16 + fr;
      float ps = 0.f;
#pragma unroll
      for (int m = 0; m < 8; ++m) {
        const long r = rowBase + wr * 128 + m * 16 + fk * 4;
        f32x4 v = acc[m][n];
        float e0 = __expf(v[0] * scale), e1 = __expf(v[1] * scale);
        float e2 = __expf(v[2] * scale), e3 = __expf(v[3] * scale);
        ps += (e0 + e1) + (e2 + e3);
        ushort4 o;
        o.x = f2bf(e0); o.y = f2bf(e1); o.z = f2bf(e2); o.w = f2bf(e3);
        *(ushort4*)((u16*)Cp + cb + c * (long)M + r) = o;
      }
      ps += __shfl_xor(ps, 16);
      ps += __shfl_xor(ps, 32);
      if (lane < 16) atomicAdd(&rsum[(long)tz * 2048 + c], ps);
    }
  } else if (MODE == 3) {
#pragma unroll
    for (int n = 0; n < 4; ++n) {
      const long c = colBase + wc * 64 + n * 16 + fr;
      const float inv = 1.f / rsum[(long)tz * 2048 + c];
#pragma unroll
      for (int m = 0; m < 8; ++m) {
        const long r = rowBase + wr * 128 + m * 16 + fk * 4;
        const long idx = cb + c * (long)M + r;
        f32x4 v = acc[m][n];
        ushort4 r1 = *(const ushort4*)(R1 + idx);
        ushort4 r2 = *(const ushort4*)(R2 + idx);
        ushort4 o;
        o.x = f2bf(v[0] * inv + bf2f(r1.x) + bf2f(r2.x));
        o.y = f2bf(v[1] * inv + bf2f(r1.y) + bf2f(r2.y));
        o.z = f2bf(v[2] * inv + bf2f(r1.z) + bf2f(r2.z));
        o.w = f2bf(v[3] * inv + bf2f(r1.w) + bf2f(r2.w));
        *(ushort4*)((u16*)Cp + idx) = o;
      }
    }
  } else {
#pragma unroll
    for (int m = 0; m < 8; ++m) {
#pragma unroll
      for (int n = 0; n < 4; ++n) {
        const long r = rowBase + wr * 128 + m * 16 + fk * 4;
        const long c = colBase + wc * 64 + n * 16 + fr;
        f32x4 v = acc[m][n];
        if (MODE == 0) {
          float4 bb = *(const float4*)(bias + r);
          ushort4 o;
          o.x = f2bf(v[0] + bb.x); o.y = f2bf(v[1] + bb.y);
          o.z = f2bf(v[2] + bb.z); o.w = f2bf(v[3] + bb.w);
          *(ushort4*)((u16*)Cp + c * (long)M + r) = o;
        } else if (MODE == 2) {
          const long b2 = r >> 11;
          const long i = r & 2047;
          const float bc = bias[c];
          ushort4 o;
          o.x = f2bf(v[0] + bc); o.y = f2bf(v[1] + bc);
          o.z = f2bf(v[2] + bc); o.w = f2bf(v[3] + bc);
          *(ushort4*)((u16*)Cp + b2 * 2097152L + c * 2048L + i) = o;
        } else {
          float4 bb = *(const float4*)(bias + r);
          float4 o;
          o.x = v[0] + bb.x; o.y = v[1] + bb.y; o.z = v[2] + bb.z; o.w = v[3] + bb.w;
          *(float4*)((float*)Cp + c * (long)M + r) = o;
        }
      }
    }
  }
#undef LDA
#undef LDB
#undef RDA
#undef RDB2
#undef MFMAQ
#undef GTILE
}

// generic wrapper
template <int MODE>
__global__ __launch_bounds__(512, 2)
void gemm256(const u16* __restrict__ A, const u16* __restrict__ B,
             const float* __restrict__ bias, void* __restrict__ Cp,
             const u16* __restrict__ R1, const u16* __restrict__ R2,
             float* __restrict__ rsum,
             int M, int N, int K, long sA, long sB, long sC, float scale,
             int ntx, int nty, int g, int fdim) {
  extern __shared__ char lds[];
  gemm_body<MODE>(A, B, bias, Cp, R1, R2, rsum, M, N, K, sA, sB, sC, scale,
                  ntx, nty, g, fdim, blockIdx.x, gridDim.x, lds);
}

// merged Q/K/V projections: blocks [0,256)=Q, [256,512)=K, [512,768)=V^T
__global__ __launch_bounds__(512, 2)
void proj3(const u16* __restrict__ Wq_b, const u16* __restrict__ Wk_b,
           const u16* __restrict__ Wv_b, const u16* __restrict__ refn,
           const u16* __restrict__ posen, const u16* __restrict__ imgn,
           const float* __restrict__ bq, const float* __restrict__ bk,
           const float* __restrict__ bv, u16* __restrict__ Qout,
           u16* __restrict__ Kout, u16* __restrict__ Vt) {
  extern __shared__ char lds[];
  const int b = blockIdx.x;
  if (b < 512) {
    const u16* A = (b < 256) ? Wq_b : Wk_b;
    const u16* B = (b < 256) ? refn : posen;
    const float* bias = (b < 256) ? bq : bk;
    u16* out = (b < 256) ? Qout : Kout;
    gemm_body<0>(A, B, bias, out, nullptr, nullptr, nullptr,
                 1024, 16384, 1024, 0, 0, 0, 1.f,
                 64, 4, 4, 0, b & 255, 256, lds);
  } else {
    gemm_body<2>(imgn, Wv_b, bv, Vt, nullptr, nullptr, nullptr,
                 16384, 1024, 1024, 0, 0, 0, 1.f,
                 4, 64, 4, 1, b - 512, 256, lds);
  }
}

// ---------- launcher ----------
extern "C" void kernel_launch(void* const* d_in, const int* in_sizes, int n_in,
                              void* d_out, int out_size, void* d_ws, size_t ws_size,
                              hipStream_t stream) {
  const float* img  = (const float*)d_in[0];
  const float* refp = (const float*)d_in[1];
  const float* pose = (const float*)d_in[2];
  const float* gam  = (const float*)d_in[3];
  const float* bet  = (const float*)d_in[4];
  const float* Wq = (const float*)d_in[5];
  const float* bq = (const float*)d_in[6];
  const float* Wk = (const float*)d_in[7];
  const float* bk = (const float*)d_in[8];
  const float* Wv = (const float*)d_in[9];
  const float* bv = (const float*)d_in[10];
  const float* Wo = (const float*)d_in[11];
  const float* bo = (const float*)d_in[12];

  char* ws = (char*)d_ws;
  const size_t MB = 1u << 20;
  u16* Wq_b = (u16*)(ws + 0 * MB);
  u16* Wk_b = (u16*)(ws + 2 * MB);
  u16* Wv_b = (u16*)(ws + 4 * MB);
  u16* Wo_b = (u16*)(ws + 6 * MB);           // 1.5 MB
  float* rowsum = (float*)(ws + 7 * MB + 512 * 1024);  // 64 KB
  u16* bufA = (u16*)(ws + 8 * MB);    // ref_n
  u16* bufB = (u16*)(ws + 40 * MB);   // pose_n
  u16* bufC = (u16*)(ws + 72 * MB);   // img_n
  u16* bufD = (u16*)(ws + 104 * MB);  // Q, later X
  u16* bufE = (u16*)(ws + 136 * MB);  // V^T
  u16* bufL = (u16*)(ws + 168 * MB);  // exp(logits) bf16 (64 MB)
  u16* Kbuf = (u16*)d_out;            // K parked in d_out (32 MB of 50.3 MB);
                                      // out-projection later overwrites ALL of d_out

  const int LDSB = 131072;
  hipFuncSetAttribute((const void*)gemm256<1>, hipFuncAttributeMaxDynamicSharedMemorySize, LDSB);
  hipFuncSetAttribute((const void*)gemm256<3>, hipFuncAttributeMaxDynamicSharedMemorySize, LDSB);
  hipFuncSetAttribute((const void*)gemm256<4>, hipFuncAttributeMaxDynamicSharedMemorySize, LDSB);
  hipFuncSetAttribute((const void*)proj3, hipFuncAttributeMaxDynamicSharedMemorySize, LDSB);

  // layernorms x3 + weight cvt + rowsum zero (one launch)
  ln_cvt<<<dim3(16384, 4), 256, 0, stream>>>(refp, pose, img, gam, bet,
                                             bufA, bufB, bufC,
                                             Wq, Wk, Wv, Wo,
                                             Wq_b, Wk_b, Wv_b, Wo_b, rowsum);

  // Q/K/V projections in one dispatch:
  //   Q[i,e] (swapped, ->bufD), K[i,e] (swapped, ->d_out scratch), V^T (MODE2 ->bufE)
  proj3<<<768, 512, LDSB, stream>>>(Wq_b, Wk_b, Wv_b, bufA, bufB, bufC,
                                    bq, bk, bv, bufD, Kbuf, bufE);

  // P[i,j] = exp((Q@K^T)/32)  (swapped: A=K, B=Q); row-sums via atomics
  gemm256<1><<<512, 512, LDSB, stream>>>(Kbuf, bufD, nullptr, bufL, nullptr, nullptr, rowsum,
                                         2048, 2048, 1024,
                                         2048L * 1024, 2048L * 1024, 2048L * 2048,
                                         0.03125f, 8, 8, 4, 0);
  // X[i,d] = (P @ V)/rowsum + pose_n + img_n  (swapped: A=V^T, B=P)
  gemm256<3><<<256, 512, LDSB, stream>>>(bufE, bufL, nullptr, bufD, bufB, bufC, rowsum,
                                         1024, 2048, 2048,
                                         1024L * 2048, 2048L * 2048, 2048L * 1024, 1.f,
                                         8, 4, 4, 0);
  // out[i,o] = X @ Wo^T + bo  (swapped: A=Wo, B=X; overwrites all of d_out)
  gemm256<4><<<192, 512, LDSB, stream>>>(Wo_b, bufD, bo, d_out, nullptr, nullptr, nullptr,
                                         768, 16384, 1024, 0, 0, 0, 1.f,
                                         64, 3, 3, 0);
}